// Round 9
// baseline (758.400 us; speedup 1.0000x reference)
//
#include <hip/hip_runtime.h>
#include <hip/hip_bf16.h>
#include <math.h>

// B=8192, D=512, V=64, E=8, hidden (1024,512,256)
// All matmuls as bf16 MFMA with hi/lo split (3 products):
//   C = Ahi*Bhi + Alo*Bhi + Ahi*Blo.  A: [M][2K] hi|lo, Bt: [N][2K] hi|lo.
// Round 9: interleaved-kind tiles — one [256][64] tile holds hi(cols 0-31) and
// lo(cols 32-63) of a 32-k slice; A,B x double-buffer = 128KB LDS. One barrier
// + one vmcnt(0) per 32-k step, 48-MFMA clusters, 24 ds_read/wave/step.

typedef short bf16x8 __attribute__((ext_vector_type(8)));
typedef float f32x4 __attribute__((ext_vector_type(4)));

#define AS1 __attribute__((address_space(1)))
#define AS3 __attribute__((address_space(3)))
#define SCHED0 __builtin_amdgcn_sched_barrier(0)
#define SBAR __builtin_amdgcn_s_barrier()

__device__ __forceinline__ ushort f2bf(float x){
  union { float f; unsigned u; } v; v.f = x;
  unsigned r = v.u + 0x7fffu + ((v.u >> 16) & 1u);
  return (ushort)(r >> 16);
}
__device__ __forceinline__ float bf2f(ushort h){
  union { unsigned u; float f; } v; v.u = ((unsigned)h) << 16; return v.f;
}
__device__ __forceinline__ float elu_f(float x){
  return x > 0.f ? x : __expf(x) - 1.f;
}

// ---- unified prep: activations ----
struct AJob { const float* X; ushort* A; int total, K; };
__global__ void prep_act_all(AJob j0, AJob j1, int t0){
  int i = blockIdx.x * 256 + threadIdx.x;
  AJob J; int idx;
  if (i < t0){ J = j0; idx = i; }
  else { J = j1; idx = i - t0; if (idx >= J.total) return; }
  int row = idx / J.K, k = idx - row * J.K;
  float x = J.X[idx];
  ushort hi = f2bf(x);
  ushort lo = f2bf(x - bf2f(hi));
  size_t base = (size_t)row * (size_t)(2 * J.K);
  J.A[base + k] = hi;
  J.A[base + J.K + k] = lo;
}

// ---- unified prep: weights f32 [E][K][N] -> [E][N][2K] bf16 hi|lo ----
struct WJob { const float* W; ushort* Bt; int K, N, nb, nk, blkStart; };
struct WJobs { WJob j[6]; int njobs; };
__global__ void prep_w_all(WJobs jobs){
  __shared__ float tile[32][33];
  int b = blockIdx.x;
  int ji = 0;
  while (ji + 1 < jobs.njobs && b >= jobs.j[ji + 1].blkStart) ji++;
  WJob J = jobs.j[ji];
  int rem = b - J.blkStart;
  int x = rem % J.nb; rem /= J.nb;
  int y = rem % J.nk; int e = rem / J.nk;
  const float* w = J.W + (size_t)e * J.K * J.N;
  ushort* bt = J.Bt + (size_t)e * J.N * 2 * J.K;
  int n0 = x * 32, k0 = y * 32;
  for (int i = threadIdx.y; i < 32; i += 8)
    tile[i][threadIdx.x] = w[(size_t)(k0 + i) * J.N + n0 + threadIdx.x];
  __syncthreads();
  for (int jj = threadIdx.y; jj < 32; jj += 8){
    float v = tile[threadIdx.x][jj];
    ushort hi = f2bf(v);
    ushort lo = f2bf(v - bf2f(hi));
    size_t base = (size_t)(n0 + jj) * (size_t)(2 * J.K);
    bt[base + k0 + threadIdx.x] = hi;
    bt[base + J.K + k0 + threadIdx.x] = lo;
  }
}

// ---- descriptor-batched 256x256 GEMM, interleaved hi|lo 32-k steps ----
// mode 0: C = split bf16 [M][2N]; mode 1: C = f32 [M][N];
// mode 2: no C — ret[row*8+eidx] = sum_col elu(acc+bias)*w3[col] + rbp[0]
struct Slice {
  const ushort* A; const ushort* Bt; const float* bias; void* C;
  const float* w3; const float* rbp; float* ret;
  int N, K, log2gx, mode, blkStart, eidx;
};
struct SliceArr { Slice s[9]; int nz; };

__global__ __launch_bounds__(512, 2) void gemm8p(SliceArr args){
  // tile [256][64]: cols 0..31 = hi k0..31, cols 32..63 = lo k0..31
  __shared__ __align__(16) ushort As[2][256][64];   // 64KB
  __shared__ __align__(16) ushort Bs[2][256][64];   // 64KB
  __shared__ float red[4][256];                     // 4KB (mode-2 reduce)

  // XCD-chunked bijective swizzle (grids here are multiples of 8)
  const int nwg  = gridDim.x;
  const int orig = blockIdx.x;
  const int wg   = (orig & 7) * (nwg >> 3) + (orig >> 3);

  int z = 0;
  while (z + 1 < args.nz && wg >= args.s[z + 1].blkStart) z++;
  const Slice sl = args.s[z];
  const int rem = wg - sl.blkStart;
  const int gxm = (1 << sl.log2gx) - 1;
  const int bx  = rem & gxm;
  const int by  = rem >> sl.log2gx;

  const ushort* __restrict__ Ag = sl.A;
  const ushort* __restrict__ Bg = sl.Bt;
  const int K = sl.K;

  const int tid  = threadIdx.x;
  const int lane = tid & 63;
  const int wave = tid >> 6;
  const int wr = wave >> 2;                     // 0..1 : rows wr*128..+127
  const int wc = wave & 3;                      // 0..3 : cols wc*64..+63
  const int rowBase = by * 256;
  const int colBase = bx * 256;
  const int KB = K >> 5;                        // 32-k steps
  const int lr = lane & 15;
  const int lk = (lane >> 4) << 3;
  const int swzR = (lr & 7) << 3;
  const size_t strideK2 = (size_t)(2 * K);

  const int rowS = tid >> 3;                    // 0..63
  const int swzS = ((tid >> 3) & 7) << 3;
  const int colS = ((tid & 7) << 3) ^ swzS;     // 0..63 combined col (kind in bit 5)

  // stage both A and B tiles of 32-k step kt into buffer buf (8 instrs/thread)
  auto stage = [&](int buf, int kt){
    int tt = (kt < KB) ? kt : (KB - 1);         // clamp: dead-but-safe
    int kA = ((colS & 32) ? K : 0) + (tt << 5) + (colS & 31);
    {
      char* lb = (char*)&As[buf][0][0];
      #pragma unroll
      for (int j = 0; j < 4; j++){
        const ushort* src = Ag + (size_t)(rowBase + j * 64 + rowS) * strideK2 + kA;
        __builtin_amdgcn_global_load_lds((const AS1 void*)src,
                                         (AS3 void*)(lb + j * 8192 + tid * 16), 16, 0, 0);
      }
    }
    {
      char* lb = (char*)&Bs[buf][0][0];
      #pragma unroll
      for (int j = 0; j < 4; j++){
        const ushort* src = Bg + (size_t)(colBase + j * 64 + rowS) * strideK2 + kA;
        __builtin_amdgcn_global_load_lds((const AS1 void*)src,
                                         (AS3 void*)(lb + j * 8192 + tid * 16), 16, 0, 0);
      }
    }
  };

  bf16x8 ah[4], al[4], bh[4], bl[4];
  auto readB = [&](int buf){
    #pragma unroll
    for (int n = 0; n < 4; n++){
      bh[n] = *(const bf16x8*)&Bs[buf][wc * 64 + n * 16 + lr][lk ^ swzR];
      bl[n] = *(const bf16x8*)&Bs[buf][wc * 64 + n * 16 + lr][(32 + lk) ^ swzR];
    }
  };
  auto readA = [&](int buf, int mh){
    #pragma unroll
    for (int m = 0; m < 4; m++){
      ah[m] = *(const bf16x8*)&As[buf][wr * 128 + mh * 64 + m * 16 + lr][lk ^ swzR];
      al[m] = *(const bf16x8*)&As[buf][wr * 128 + mh * 64 + m * 16 + lr][(32 + lk) ^ swzR];
    }
  };

  f32x4 acc[8][4];
  #pragma unroll
  for (int m = 0; m < 8; m++)
    #pragma unroll
    for (int n = 0; n < 4; n++)
      acc[m][n] = (f32x4){0.f, 0.f, 0.f, 0.f};

  auto mfmaH = [&](int mh){
    #pragma unroll
    for (int m = 0; m < 4; m++)
      #pragma unroll
      for (int n = 0; n < 4; n++){
        f32x4 c = acc[mh * 4 + m][n];
        c = __builtin_amdgcn_mfma_f32_16x16x32_bf16(al[m], bh[n], c, 0, 0, 0);
        c = __builtin_amdgcn_mfma_f32_16x16x32_bf16(ah[m], bh[n], c, 0, 0, 0);
        c = __builtin_amdgcn_mfma_f32_16x16x32_bf16(ah[m], bl[n], c, 0, 0, 0);
        acc[mh * 4 + m][n] = c;
      }
  };

  // prologue
  stage(0, 0);
  asm volatile("s_waitcnt vmcnt(0)" ::: "memory");
  SCHED0; SBAR; SCHED0;

  int buf = 0;
  for (int t = 0; t < KB; ++t){
    stage(buf ^ 1, t + 1);                      // 8 VMEM, full-step cover
    readB(buf);
    readA(buf, 0);
    asm volatile("s_waitcnt lgkmcnt(0)" ::: "memory"); SCHED0;
    __builtin_amdgcn_s_setprio(1); mfmaH(0); __builtin_amdgcn_s_setprio(0);
    readA(buf, 1);
    asm volatile("s_waitcnt lgkmcnt(0)" ::: "memory"); SCHED0;
    __builtin_amdgcn_s_setprio(1); mfmaH(1); __builtin_amdgcn_s_setprio(0);
    SCHED0;
    asm volatile("s_waitcnt vmcnt(0)" ::: "memory");
    SBAR; SCHED0;
    buf ^= 1;
  }

  // ---- epilogue ----
  // acc[m8][n]: row = rowBase + wr*128 + (m8>>2)*64 + (m8&3)*16 + (lane>>4)*4 + r
  //             col = colBase + wc*64 + n*16 + lr
  if (sl.mode == 2){
    __syncthreads();
    #pragma unroll
    for (int m = 0; m < 8; m++){
      float p4[4] = {0.f, 0.f, 0.f, 0.f};
      #pragma unroll
      for (int n = 0; n < 4; n++){
        int col = colBase + wc * 64 + n * 16 + lr;
        float bv = sl.bias[col];
        float wv = sl.w3[col];
        #pragma unroll
        for (int r = 0; r < 4; r++)
          p4[r] += elu_f(acc[m][n][r] + bv) * wv;
      }
      #pragma unroll
      for (int r = 0; r < 4; r++){
        #pragma unroll
        for (int s = 8; s > 0; s >>= 1) p4[r] += __shfl_xor(p4[r], s, 64);
      }
      if ((lane & 15) == 0){
        int hig = lane >> 4;
        int rowoff = wr * 128 + ((m >> 2) << 6) + ((m & 3) << 4) + hig * 4;
        #pragma unroll
        for (int r = 0; r < 4; r++)
          red[wc][rowoff + r] = p4[r];
      }
    }
    __syncthreads();
    if (tid < 256){
      float s4 = red[0][tid] + red[1][tid] + red[2][tid] + red[3][tid];
      sl.ret[(size_t)(rowBase + tid) * 8 + sl.eidx] = s4 + sl.rbp[0];
    }
    return;
  }

  const int N = sl.N;
  #pragma unroll
  for (int m = 0; m < 8; m++){
    int row0 = rowBase + wr * 128 + ((m >> 2) << 6) + ((m & 3) << 4) + ((lane >> 4) << 2);
    #pragma unroll
    for (int n = 0; n < 4; n++){
      int col = colBase + wc * 64 + n * 16 + lr;
      float bv = sl.bias[col];
      float v0 = elu_f(acc[m][n][0] + bv);
      float v1 = elu_f(acc[m][n][1] + bv);
      float v2 = elu_f(acc[m][n][2] + bv);
      float v3 = elu_f(acc[m][n][3] + bv);
      if (sl.mode == 0){
        unsigned ph01, ph23, pl01, pl23;
        asm("v_cvt_pk_bf16_f32 %0, %1, %2" : "=v"(ph01) : "v"(v0), "v"(v1));
        asm("v_cvt_pk_bf16_f32 %0, %1, %2" : "=v"(ph23) : "v"(v2), "v"(v3));
        union { unsigned u; float f; } c0, c1, c2, c3;
        c0.u = ph01 << 16; c1.u = ph01 & 0xffff0000u;
        c2.u = ph23 << 16; c3.u = ph23 & 0xffff0000u;
        asm("v_cvt_pk_bf16_f32 %0, %1, %2" : "=v"(pl01) : "v"(v0 - c0.f), "v"(v1 - c1.f));
        asm("v_cvt_pk_bf16_f32 %0, %1, %2" : "=v"(pl23) : "v"(v2 - c2.f), "v"(v3 - c3.f));
        ushort* C = (ushort*)sl.C;
        size_t s2n = (size_t)(2 * N);
        size_t r0b = (size_t)row0 * s2n + col;
        C[r0b]            = (ushort)ph01;
        C[r0b + s2n]      = (ushort)(ph01 >> 16);
        C[r0b + 2 * s2n]  = (ushort)ph23;
        C[r0b + 3 * s2n]  = (ushort)(ph23 >> 16);
        size_t r0l = r0b + N;
        C[r0l]            = (ushort)pl01;
        C[r0l + s2n]      = (ushort)(pl01 >> 16);
        C[r0l + 2 * s2n]  = (ushort)pl23;
        C[r0l + 3 * s2n]  = (ushort)(pl23 >> 16);
      } else {
        float* C = (float*)sl.C;
        size_t r0b = (size_t)row0 * N + col;
        C[r0b]         = v0;
        C[r0b + N]     = v1;
        C[r0b + 2 * N] = v2;
        C[r0b + 3 * N] = v3;
      }
    }
  }
}

// ---- gate final layer + softmax ----
__global__ void gate3_softmax(const float* __restrict__ g2, const float* __restrict__ gw3,
                              const float* __restrict__ gb3, float* __restrict__ wts){
  int row = blockIdx.x * 4 + (threadIdx.x >> 6);
  int lane = threadIdx.x & 63;
  const float* g = g2 + (size_t)row * 256;
  float p[8];
  #pragma unroll
  for (int j = 0; j < 8; j++) p[j] = 0.f;
  for (int k = lane; k < 256; k += 64){
    float x = g[k];
    #pragma unroll
    for (int j = 0; j < 8; j++) p[j] += x * gw3[k * 8 + j];
  }
  #pragma unroll
  for (int j = 0; j < 8; j++){
    #pragma unroll
    for (int s = 32; s > 0; s >>= 1) p[j] += __shfl_xor(p[j], s, 64);
  }
  float mx = -1e30f;
  #pragma unroll
  for (int j = 0; j < 8; j++){ p[j] += gb3[j]; mx = fmaxf(mx, p[j]); }
  float sum = 0.f;
  #pragma unroll
  for (int j = 0; j < 8; j++){ p[j] = expf(p[j] - mx); sum += p[j]; }
  float inv = 1.f / sum;
  #pragma unroll
  for (int j = 0; j < 8; j++)
    if (lane == j) wts[(size_t)row * 8 + j] = p[j] * inv;
}

// ---- final combine ----
__global__ void combine(const float* __restrict__ wts, const float* __restrict__ ret,
                        float* __restrict__ out){
  int i = blockIdx.x * blockDim.x + threadIdx.x;
  if (i >= 8192) return;
  float s = 0.f;
  #pragma unroll
  for (int j = 0; j < 8; j++) s += wts[(size_t)i * 8 + j] * ret[(size_t)i * 8 + j];
  out[i] = s;
}

extern "C" void kernel_launch(void* const* d_in, const int* in_sizes, int n_in,
                              void* d_out, int out_size, void* d_ws, size_t ws_size,
                              hipStream_t stream){
  const float* obs  = (const float*)d_in[0];
  const float* code = (const float*)d_in[1];
  const float* ew0  = (const float*)d_in[2];
  const float* eb0  = (const float*)d_in[3];
  const float* ew1  = (const float*)d_in[4];
  const float* eb1  = (const float*)d_in[5];
  const float* ew2  = (const float*)d_in[6];
  const float* eb2  = (const float*)d_in[7];
  const float* ew3  = (const float*)d_in[8];
  const float* eb3  = (const float*)d_in[9];
  const float* gw0  = (const float*)d_in[10];
  const float* gb0  = (const float*)d_in[11];
  const float* gw1  = (const float*)d_in[12];
  const float* gb1  = (const float*)d_in[13];
  const float* gw2  = (const float*)d_in[14];
  const float* gb2  = (const float*)d_in[15];
  const float* gw3  = (const float*)d_in[16];
  const float* gb3  = (const float*)d_in[17];
  (void)in_sizes; (void)n_in; (void)out_size;

  char* ws = (char*)d_ws;
  size_t off = 0;
  auto alloc = [&](size_t bytes) -> void* {
    void* p = ws + off;
    off += (bytes + 255) & ~(size_t)255;
    return p;
  };
  ushort* A_obs  = (ushort*)alloc(8192ull * 1024 * 2);
  ushort* A_code = (ushort*)alloc(8192ull * 128 * 2);
  ushort* B_ew0  = (ushort*)alloc(8ull * 1024 * 1024 * 2);
  ushort* B_ew1  = (ushort*)alloc(8ull * 512 * 2048 * 2);
  ushort* B_ew2  = (ushort*)alloc(8ull * 256 * 1024 * 2);
  ushort* B_gw0  = (ushort*)alloc(1024ull * 128 * 2);
  ushort* B_gw1  = (ushort*)alloc(512ull * 2048 * 2);
  ushort* B_gw2  = (ushort*)alloc(256ull * 1024 * 2);
  float*  wts    = (float*)alloc(8192ull * 8 * 4);
  float*  ret    = (float*)alloc(8192ull * 8 * 4);
  const size_t fixed = off;

  const size_t sl0b = 8192ull * 2048 * 2;   // h0 split bf16 (32MiB)
  const size_t sl1b = 8192ull * 1024 * 2;   // h1 split bf16 (16MiB)
  const size_t pairB = sl0b + sl1b;

  int G = 0;
  {
    const int cand[5] = {8, 4, 3, 2, 1};
    for (int ci = 0; ci < 5; ci++)
      if (fixed + (size_t)(cand[ci] + 1) * pairB <= ws_size){ G = cand[ci]; break; }
  }
  const bool gateFirst = (G == 0);
  const int ns = gateFirst ? 1 : (G + 1);
  ushort* h0buf = (ushort*)alloc((size_t)ns * sl0b);
  ushort* h1buf = (ushort*)alloc((size_t)ns * sl1b);
  const size_t sl0e = 8192ull * 2048;
  const size_t sl1e = 8192ull * 1024;
  const int gsl = ns - 1;
  ushort* h0g = h0buf + (size_t)gsl * sl0e;
  ushort* h1g = h1buf + (size_t)gsl * sl1e;
  float*  h2g = (float*)h0g;                 // alias: h0g dead after gate L1

  // prep (2 dispatches)
  {
    AJob j0 = {obs,  A_obs,  8192 * 512, 512};
    AJob j1 = {code, A_code, 8192 * 64,  64};
    int t0 = 8192 * 512;
    prep_act_all<<<dim3((t0 + j1.total + 255) / 256), 256, 0, stream>>>(j0, j1, t0);

    WJobs wj; wj.njobs = 6;
    int bs = 0;
    auto addW = [&](int i, const float* W, ushort* Bt, int K, int N, int E){
      wj.j[i] = {W, Bt, K, N, N / 32, K / 32, bs};
      bs += E * (N / 32) * (K / 32);
    };
    addW(0, ew0, B_ew0, 512, 1024, 8);
    addW(1, ew1, B_ew1, 1024, 512, 8);
    addW(2, ew2, B_ew2, 512, 256, 8);
    addW(3, gw0, B_gw0, 64, 1024, 1);
    addW(4, gw1, B_gw1, 1024, 512, 1);
    addW(5, gw2, B_gw2, 512, 256, 1);
    prep_w_all<<<dim3(bs), dim3(32, 8), 0, stream>>>(wj);
  }

  auto runGroup = [&](int e0, int cnt, bool withGate){
    SliceArr sa; int nb;
    // L0
    nb = 0; sa.nz = cnt + (withGate ? 1 : 0);
    for (int i = 0; i < cnt; i++){ int e = e0 + i;
      sa.s[i] = {A_obs, B_ew0 + (size_t)e * 1024 * 1024, eb0 + e * 1024,
                 h0buf + (size_t)i * sl0e, nullptr, nullptr, nullptr,
                 1024, 512, 2, 0, nb, 0};
      nb += 4 * 32;
    }
    if (withGate){
      sa.s[cnt] = {A_code, B_gw0, gb0, h0g, nullptr, nullptr, nullptr,
                   1024, 64, 2, 0, nb, 0};
      nb += 4 * 32;
    }
    for (int i = sa.nz; i < 9; i++) sa.s[i] = sa.s[0];
    gemm8p<<<dim3(nb), 512, 0, stream>>>(sa);
    // L1
    nb = 0;
    for (int i = 0; i < cnt; i++){ int e = e0 + i;
      sa.s[i] = {h0buf + (size_t)i * sl0e, B_ew1 + (size_t)e * 512 * 2048, eb1 + e * 512,
                 h1buf + (size_t)i * sl1e, nullptr, nullptr, nullptr,
                 512, 1024, 1, 0, nb, 0};
      nb += 2 * 32;
    }
    if (withGate){
      sa.s[cnt] = {h0g, B_gw1, gb1, h1g, nullptr, nullptr, nullptr,
                   512, 1024, 1, 0, nb, 0};
      nb += 2 * 32;
    }
    gemm8p<<<dim3(nb), 512, 0, stream>>>(sa);
    // L2: experts fused-returns (mode 2); gate f32 h2 (mode 1)
    nb = 0;
    for (int i = 0; i < cnt; i++){ int e = e0 + i;
      sa.s[i] = {h1buf + (size_t)i * sl1e, B_ew2 + (size_t)e * 256 * 1024, eb2 + e * 256,
                 nullptr, ew3 + (size_t)e * 256, eb3 + e, ret,
                 256, 512, 0, 2, nb, e};
      nb += 32;
    }
    if (withGate){
      sa.s[cnt] = {h1g, B_gw2, gb2, h2g, nullptr, nullptr, nullptr,
                   256, 512, 0, 1, nb, 0};
      nb += 32;
    }
    gemm8p<<<dim3(nb), 512, 0, stream>>>(sa);
    if (withGate)
      gate3_softmax<<<dim3(2048), 256, 0, stream>>>(h2g, gw3, gb3, wts);
  };

  if (gateFirst){
    SliceArr sa; sa.nz = 1;
    sa.s[0] = {A_code, B_gw0, gb0, h0g, nullptr, nullptr, nullptr, 1024, 64, 2, 0, 0, 0};
    for (int i = 1; i < 9; i++) sa.s[i] = sa.s[0];
    gemm8p<<<dim3(128), 512, 0, stream>>>(sa);
    sa.s[0] = {h0g, B_gw1, gb1, h1g, nullptr, nullptr, nullptr, 512, 1024, 1, 0, 0, 0};
    gemm8p<<<dim3(64), 512, 0, stream>>>(sa);
    sa.s[0] = {h1g, B_gw2, gb2, h2g, nullptr, nullptr, nullptr, 256, 512, 0, 1, 0, 0};
    gemm8p<<<dim3(32), 512, 0, stream>>>(sa);
    gate3_softmax<<<dim3(2048), 256, 0, stream>>>(h2g, gw3, gb3, wts);
    for (int e = 0; e < 8; e++) runGroup(e, 1, false);
  } else {
    bool first = true;
    for (int e0 = 0; e0 < 8; ){
      int cnt = (8 - e0 < G) ? (8 - e0) : G;
      runGroup(e0, cnt, first);
      first = false;
      e0 += cnt;
    }
  }

  combine<<<dim3(8192 / 256), 256, 0, stream>>>(wts, ret, (float*)d_out);
}

// Round 10
// 636.462 us; speedup vs baseline: 1.1916x; 1.1916x over previous
//
#include <hip/hip_runtime.h>
#include <hip/hip_bf16.h>
#include <math.h>

// B=8192, D=512, V=64, E=8, hidden (1024,512,256)
// All matmuls as bf16 MFMA with hi/lo split (3 products):
//   C = Ahi*Bhi + Alo*Bhi + Ahi*Blo.  A: [M][2K] hi|lo, Bt: [N][2K] hi|lo.
// Round 10: occupancy over tile size — 128x128 tile, 4 waves, single 33KB
// LDS buffer -> 3 blocks/CU. m97-style 2-barrier K-step (read-all, free,
// stage-next, 48-MFMA cluster). Fused-returns via per-col-half partials.

typedef short bf16x8 __attribute__((ext_vector_type(8)));
typedef float f32x4 __attribute__((ext_vector_type(4)));

#define AS1 __attribute__((address_space(1)))
#define AS3 __attribute__((address_space(3)))
#define SCHED0 __builtin_amdgcn_sched_barrier(0)
#define SBAR __builtin_amdgcn_s_barrier()

__device__ __forceinline__ ushort f2bf(float x){
  union { float f; unsigned u; } v; v.f = x;
  unsigned r = v.u + 0x7fffu + ((v.u >> 16) & 1u);
  return (ushort)(r >> 16);
}
__device__ __forceinline__ float bf2f(ushort h){
  union { unsigned u; float f; } v; v.u = ((unsigned)h) << 16; return v.f;
}
__device__ __forceinline__ float elu_f(float x){
  return x > 0.f ? x : __expf(x) - 1.f;
}

// ---- unified prep: activations ----
struct AJob { const float* X; ushort* A; int total, K; };
__global__ void prep_act_all(AJob j0, AJob j1, int t0){
  int i = blockIdx.x * 256 + threadIdx.x;
  AJob J; int idx;
  if (i < t0){ J = j0; idx = i; }
  else { J = j1; idx = i - t0; if (idx >= J.total) return; }
  int row = idx / J.K, k = idx - row * J.K;
  float x = J.X[idx];
  ushort hi = f2bf(x);
  ushort lo = f2bf(x - bf2f(hi));
  size_t base = (size_t)row * (size_t)(2 * J.K);
  J.A[base + k] = hi;
  J.A[base + J.K + k] = lo;
}

// ---- unified prep: weights f32 [E][K][N] -> [E][N][2K] bf16 hi|lo ----
struct WJob { const float* W; ushort* Bt; int K, N, nb, nk, blkStart; };
struct WJobs { WJob j[6]; int njobs; };
__global__ void prep_w_all(WJobs jobs){
  __shared__ float tile[32][33];
  int b = blockIdx.x;
  int ji = 0;
  while (ji + 1 < jobs.njobs && b >= jobs.j[ji + 1].blkStart) ji++;
  WJob J = jobs.j[ji];
  int rem = b - J.blkStart;
  int x = rem % J.nb; rem /= J.nb;
  int y = rem % J.nk; int e = rem / J.nk;
  const float* w = J.W + (size_t)e * J.K * J.N;
  ushort* bt = J.Bt + (size_t)e * J.N * 2 * J.K;
  int n0 = x * 32, k0 = y * 32;
  for (int i = threadIdx.y; i < 32; i += 8)
    tile[i][threadIdx.x] = w[(size_t)(k0 + i) * J.N + n0 + threadIdx.x];
  __syncthreads();
  for (int jj = threadIdx.y; jj < 32; jj += 8){
    float v = tile[threadIdx.x][jj];
    ushort hi = f2bf(v);
    ushort lo = f2bf(v - bf2f(hi));
    size_t base = (size_t)(n0 + jj) * (size_t)(2 * J.K);
    bt[base + k0 + threadIdx.x] = hi;
    bt[base + J.K + k0 + threadIdx.x] = lo;
  }
}

// ---- descriptor-batched 128x128 GEMM, interleaved hi|lo 32-k steps ----
// mode 0: C = split bf16 [M][2N]; mode 1: C = f32 [M][N];
// mode 2: no C — ret[bx][row][eidx] = sum over THIS col-half of elu(acc+bias)*w3
struct Slice {
  const ushort* A; const ushort* Bt; const float* bias; void* C;
  const float* w3; const float* rbp; float* ret;
  int N, K, log2gx, mode, blkStart, eidx;
};
struct SliceArr { Slice s[9]; int nz; };

__global__ __launch_bounds__(256, 3) void gemm8p(SliceArr args){
  // tile [128][64]: cols 0..31 = hi k0..31, cols 32..63 = lo k0..31
  __shared__ __align__(16) ushort As[128][64];   // 16KB
  __shared__ __align__(16) ushort Bs[128][64];   // 16KB
  __shared__ float red[2][128];                  // 1KB (mode-2 reduce)

  // XCD-chunked bijective swizzle (grids here are multiples of 8)
  const int nwg  = gridDim.x;
  const int orig = blockIdx.x;
  const int wg   = (orig & 7) * (nwg >> 3) + (orig >> 3);

  int z = 0;
  while (z + 1 < args.nz && wg >= args.s[z + 1].blkStart) z++;
  const Slice sl = args.s[z];
  const int rem = wg - sl.blkStart;
  const int gxm = (1 << sl.log2gx) - 1;
  const int bx  = rem & gxm;
  const int by  = rem >> sl.log2gx;

  const ushort* __restrict__ Ag = sl.A;
  const ushort* __restrict__ Bg = sl.Bt;
  const int K = sl.K;

  const int tid  = threadIdx.x;
  const int lane = tid & 63;
  const int wave = tid >> 6;                    // 0..3
  const int wr = wave >> 1;                     // 0..1 : rows wr*64..+63
  const int wc = wave & 1;                      // 0..1 : cols wc*64..+63
  const int rowBase = by * 128;
  const int colBase = bx * 128;
  const int KB = K >> 5;                        // 32-k steps
  const int lr = lane & 15;
  const int lk = (lane >> 4) << 3;
  const int swzR = (lr & 7) << 3;
  const size_t strideK2 = (size_t)(2 * K);

  const int rowS = tid >> 3;                    // 0..31
  const int swzS = ((tid >> 3) & 7) << 3;
  const int colS = ((tid & 7) << 3) ^ swzS;     // 0..63 combined col (kind in bit 5)

  // stage A+B tiles of 32-k step kt (8 instrs/thread, 32KB total)
  auto stage = [&](int kt){
    int tt = (kt < KB) ? kt : (KB - 1);         // clamp: dead-but-safe
    int kA = ((colS & 32) ? K : 0) + (tt << 5) + (colS & 31);
    {
      char* lb = (char*)&As[0][0];
      #pragma unroll
      for (int j = 0; j < 4; j++){
        const ushort* src = Ag + (size_t)(rowBase + j * 32 + rowS) * strideK2 + kA;
        __builtin_amdgcn_global_load_lds((const AS1 void*)src,
                                         (AS3 void*)(lb + j * 4096 + tid * 16), 16, 0, 0);
      }
    }
    {
      char* lb = (char*)&Bs[0][0];
      #pragma unroll
      for (int j = 0; j < 4; j++){
        const ushort* src = Bg + (size_t)(colBase + j * 32 + rowS) * strideK2 + kA;
        __builtin_amdgcn_global_load_lds((const AS1 void*)src,
                                         (AS3 void*)(lb + j * 4096 + tid * 16), 16, 0, 0);
      }
    }
  };

  bf16x8 ah[4], al[4], bh[4], bl[4];
  auto readAll = [&](){
    #pragma unroll
    for (int n = 0; n < 4; n++){
      bh[n] = *(const bf16x8*)&Bs[wc * 64 + n * 16 + lr][lk ^ swzR];
      bl[n] = *(const bf16x8*)&Bs[wc * 64 + n * 16 + lr][(32 + lk) ^ swzR];
    }
    #pragma unroll
    for (int m = 0; m < 4; m++){
      ah[m] = *(const bf16x8*)&As[wr * 64 + m * 16 + lr][lk ^ swzR];
      al[m] = *(const bf16x8*)&As[wr * 64 + m * 16 + lr][(32 + lk) ^ swzR];
    }
  };

  f32x4 acc[4][4];
  #pragma unroll
  for (int m = 0; m < 4; m++)
    #pragma unroll
    for (int n = 0; n < 4; n++)
      acc[m][n] = (f32x4){0.f, 0.f, 0.f, 0.f};

  // prologue
  stage(0);

  for (int t = 0; t < KB; ++t){
    asm volatile("s_waitcnt vmcnt(0)" ::: "memory");  // tile t landed
    SCHED0; SBAR; SCHED0;                             // visible to all
    readAll();
    asm volatile("s_waitcnt lgkmcnt(0)" ::: "memory"); SCHED0;
    SBAR; SCHED0;                                     // buffer free chipwide
    stage(t + 1); SCHED0;                             // DMA rides under MFMA
    __builtin_amdgcn_s_setprio(1);
    #pragma unroll
    for (int m = 0; m < 4; m++)
      #pragma unroll
      for (int n = 0; n < 4; n++){
        f32x4 c = acc[m][n];
        c = __builtin_amdgcn_mfma_f32_16x16x32_bf16(al[m], bh[n], c, 0, 0, 0);
        c = __builtin_amdgcn_mfma_f32_16x16x32_bf16(ah[m], bh[n], c, 0, 0, 0);
        c = __builtin_amdgcn_mfma_f32_16x16x32_bf16(ah[m], bl[n], c, 0, 0, 0);
        acc[m][n] = c;
      }
    __builtin_amdgcn_s_setprio(0);
    SCHED0;
  }
  asm volatile("s_waitcnt vmcnt(0)" ::: "memory");    // drain dead last stage

  // ---- epilogue ----
  // acc[m][n]: row = rowBase + wr*64 + m*16 + (lane>>4)*4 + r
  //            col = colBase + wc*64 + n*16 + lr
  if (sl.mode == 2){
    // fused final expert layer, partial over this 128-col half
    __syncthreads();
    #pragma unroll
    for (int m = 0; m < 4; m++){
      float p4[4] = {0.f, 0.f, 0.f, 0.f};
      #pragma unroll
      for (int n = 0; n < 4; n++){
        int col = colBase + wc * 64 + n * 16 + lr;
        float bv = sl.bias[col];
        float wv = sl.w3[col];
        #pragma unroll
        for (int r = 0; r < 4; r++)
          p4[r] += elu_f(acc[m][n][r] + bv) * wv;
      }
      #pragma unroll
      for (int r = 0; r < 4; r++){
        #pragma unroll
        for (int s = 8; s > 0; s >>= 1) p4[r] += __shfl_xor(p4[r], s, 64);
      }
      if ((lane & 15) == 0){
        int hig = lane >> 4;
        int rowoff = wr * 64 + m * 16 + hig * 4;
        #pragma unroll
        for (int r = 0; r < 4; r++)
          red[wc][rowoff + r] = p4[r];
      }
    }
    __syncthreads();
    if (tid < 128){
      float s2 = red[0][tid] + red[1][tid];
      sl.ret[((size_t)bx * 8192 + rowBase + tid) * 8 + sl.eidx] = s2;  // bias added in combine
    }
    return;
  }

  const int N = sl.N;
  #pragma unroll
  for (int m = 0; m < 4; m++){
    int row0 = rowBase + wr * 64 + m * 16 + ((lane >> 4) << 2);
    #pragma unroll
    for (int n = 0; n < 4; n++){
      int col = colBase + wc * 64 + n * 16 + lr;
      float bv = sl.bias[col];
      float v0 = elu_f(acc[m][n][0] + bv);
      float v1 = elu_f(acc[m][n][1] + bv);
      float v2 = elu_f(acc[m][n][2] + bv);
      float v3 = elu_f(acc[m][n][3] + bv);
      if (sl.mode == 0){
        unsigned ph01, ph23, pl01, pl23;
        asm("v_cvt_pk_bf16_f32 %0, %1, %2" : "=v"(ph01) : "v"(v0), "v"(v1));
        asm("v_cvt_pk_bf16_f32 %0, %1, %2" : "=v"(ph23) : "v"(v2), "v"(v3));
        union { unsigned u; float f; } c0, c1, c2, c3;
        c0.u = ph01 << 16; c1.u = ph01 & 0xffff0000u;
        c2.u = ph23 << 16; c3.u = ph23 & 0xffff0000u;
        asm("v_cvt_pk_bf16_f32 %0, %1, %2" : "=v"(pl01) : "v"(v0 - c0.f), "v"(v1 - c1.f));
        asm("v_cvt_pk_bf16_f32 %0, %1, %2" : "=v"(pl23) : "v"(v2 - c2.f), "v"(v3 - c3.f));
        ushort* C = (ushort*)sl.C;
        size_t s2n = (size_t)(2 * N);
        size_t r0b = (size_t)row0 * s2n + col;
        C[r0b]            = (ushort)ph01;
        C[r0b + s2n]      = (ushort)(ph01 >> 16);
        C[r0b + 2 * s2n]  = (ushort)ph23;
        C[r0b + 3 * s2n]  = (ushort)(ph23 >> 16);
        size_t r0l = r0b + N;
        C[r0l]            = (ushort)pl01;
        C[r0l + s2n]      = (ushort)(pl01 >> 16);
        C[r0l + 2 * s2n]  = (ushort)pl23;
        C[r0l + 3 * s2n]  = (ushort)(pl23 >> 16);
      } else {
        float* C = (float*)sl.C;
        size_t r0b = (size_t)row0 * N + col;
        C[r0b]         = v0;
        C[r0b + N]     = v1;
        C[r0b + 2 * N] = v2;
        C[r0b + 3 * N] = v3;
      }
    }
  }
}

// ---- gate final layer + softmax ----
__global__ void gate3_softmax(const float* __restrict__ g2, const float* __restrict__ gw3,
                              const float* __restrict__ gb3, float* __restrict__ wts){
  int row = blockIdx.x * 4 + (threadIdx.x >> 6);
  int lane = threadIdx.x & 63;
  const float* g = g2 + (size_t)row * 256;
  float p[8];
  #pragma unroll
  for (int j = 0; j < 8; j++) p[j] = 0.f;
  for (int k = lane; k < 256; k += 64){
    float x = g[k];
    #pragma unroll
    for (int j = 0; j < 8; j++) p[j] += x * gw3[k * 8 + j];
  }
  #pragma unroll
  for (int j = 0; j < 8; j++){
    #pragma unroll
    for (int s = 32; s > 0; s >>= 1) p[j] += __shfl_xor(p[j], s, 64);
  }
  float mx = -1e30f;
  #pragma unroll
  for (int j = 0; j < 8; j++){ p[j] += gb3[j]; mx = fmaxf(mx, p[j]); }
  float sum = 0.f;
  #pragma unroll
  for (int j = 0; j < 8; j++){ p[j] = expf(p[j] - mx); sum += p[j]; }
  float inv = 1.f / sum;
  #pragma unroll
  for (int j = 0; j < 8; j++)
    if (lane == j) wts[(size_t)row * 8 + j] = p[j] * inv;
}

// ---- final combine: ret2 holds two col-half partials; add eb3 here ----
__global__ void combine(const float* __restrict__ wts, const float* __restrict__ ret2,
                        const float* __restrict__ eb3, float* __restrict__ out){
  int i = blockIdx.x * blockDim.x + threadIdx.x;
  if (i >= 8192) return;
  float s = 0.f;
  #pragma unroll
  for (int j = 0; j < 8; j++){
    float r = ret2[(size_t)i * 8 + j] + ret2[65536 + (size_t)i * 8 + j] + eb3[j];
    s += wts[(size_t)i * 8 + j] * r;
  }
  out[i] = s;
}

extern "C" void kernel_launch(void* const* d_in, const int* in_sizes, int n_in,
                              void* d_out, int out_size, void* d_ws, size_t ws_size,
                              hipStream_t stream){
  const float* obs  = (const float*)d_in[0];
  const float* code = (const float*)d_in[1];
  const float* ew0  = (const float*)d_in[2];
  const float* eb0  = (const float*)d_in[3];
  const float* ew1  = (const float*)d_in[4];
  const float* eb1  = (const float*)d_in[5];
  const float* ew2  = (const float*)d_in[6];
  const float* eb2  = (const float*)d_in[7];
  const float* ew3  = (const float*)d_in[8];
  const float* eb3  = (const float*)d_in[9];
  const float* gw0  = (const float*)d_in[10];
  const float* gb0  = (const float*)d_in[11];
  const float* gw1  = (const float*)d_in[12];
  const float* gb1  = (const float*)d_in[13];
  const float* gw2  = (const float*)d_in[14];
  const float* gb2  = (const float*)d_in[15];
  const float* gw3  = (const float*)d_in[16];
  const float* gb3  = (const float*)d_in[17];
  (void)in_sizes; (void)n_in; (void)out_size;

  char* ws = (char*)d_ws;
  size_t off = 0;
  auto alloc = [&](size_t bytes) -> void* {
    void* p = ws + off;
    off += (bytes + 255) & ~(size_t)255;
    return p;
  };
  ushort* A_obs  = (ushort*)alloc(8192ull * 1024 * 2);
  ushort* A_code = (ushort*)alloc(8192ull * 128 * 2);
  ushort* B_ew0  = (ushort*)alloc(8ull * 1024 * 1024 * 2);
  ushort* B_ew1  = (ushort*)alloc(8ull * 512 * 2048 * 2);
  ushort* B_ew2  = (ushort*)alloc(8ull * 256 * 1024 * 2);
  ushort* B_gw0  = (ushort*)alloc(1024ull * 128 * 2);
  ushort* B_gw1  = (ushort*)alloc(512ull * 2048 * 2);
  ushort* B_gw2  = (ushort*)alloc(256ull * 1024 * 2);
  float*  wts    = (float*)alloc(8192ull * 8 * 4);
  float*  ret2   = (float*)alloc(2ull * 8192 * 8 * 4);   // two col-half partials
  const size_t fixed = off;

  const size_t sl0b = 8192ull * 2048 * 2;   // h0 split bf16 (32MiB)
  const size_t sl1b = 8192ull * 1024 * 2;   // h1 split bf16 (16MiB)
  const size_t pairB = sl0b + sl1b;

  int G = 0;
  {
    const int cand[5] = {8, 4, 3, 2, 1};
    for (int ci = 0; ci < 5; ci++)
      if (fixed + (size_t)(cand[ci] + 1) * pairB <= ws_size){ G = cand[ci]; break; }
  }
  const bool gateFirst = (G == 0);
  const int ns = gateFirst ? 1 : (G + 1);
  ushort* h0buf = (ushort*)alloc((size_t)ns * sl0b);
  ushort* h1buf = (ushort*)alloc((size_t)ns * sl1b);
  const size_t sl0e = 8192ull * 2048;
  const size_t sl1e = 8192ull * 1024;
  const int gsl = ns - 1;
  ushort* h0g = h0buf + (size_t)gsl * sl0e;
  ushort* h1g = h1buf + (size_t)gsl * sl1e;
  float*  h2g = (float*)h0g;                 // alias: h0g dead after gate L1

  // prep (2 dispatches)
  {
    AJob j0 = {obs,  A_obs,  8192 * 512, 512};
    AJob j1 = {code, A_code, 8192 * 64,  64};
    int t0 = 8192 * 512;
    prep_act_all<<<dim3((t0 + j1.total + 255) / 256), 256, 0, stream>>>(j0, j1, t0);

    WJobs wj; wj.njobs = 6;
    int bs = 0;
    auto addW = [&](int i, const float* W, ushort* Bt, int K, int N, int E){
      wj.j[i] = {W, Bt, K, N, N / 32, K / 32, bs};
      bs += E * (N / 32) * (K / 32);
    };
    addW(0, ew0, B_ew0, 512, 1024, 8);
    addW(1, ew1, B_ew1, 1024, 512, 8);
    addW(2, ew2, B_ew2, 512, 256, 8);
    addW(3, gw0, B_gw0, 64, 1024, 1);
    addW(4, gw1, B_gw1, 1024, 512, 1);
    addW(5, gw2, B_gw2, 512, 256, 1);
    prep_w_all<<<dim3(bs), dim3(32, 8), 0, stream>>>(wj);
  }

  // per-slice block counts at 128x128 tiles
  const int NB0 = 8 * 64;    // L0: N=1024 -> gx=8,  gy=64 -> 512
  const int NB1 = 4 * 64;    // L1: N=512  -> gx=4          -> 256
  const int NB2 = 2 * 64;    // L2: N=256  -> gx=2          -> 128

  auto runGroup = [&](int e0, int cnt, bool withGate){
    SliceArr sa; int nb;
    // L0
    nb = 0; sa.nz = cnt + (withGate ? 1 : 0);
    for (int i = 0; i < cnt; i++){ int e = e0 + i;
      sa.s[i] = {A_obs, B_ew0 + (size_t)e * 1024 * 1024, eb0 + e * 1024,
                 h0buf + (size_t)i * sl0e, nullptr, nullptr, nullptr,
                 1024, 512, 3, 0, nb, 0};
      nb += NB0;
    }
    if (withGate){
      sa.s[cnt] = {A_code, B_gw0, gb0, h0g, nullptr, nullptr, nullptr,
                   1024, 64, 3, 0, nb, 0};
      nb += NB0;
    }
    for (int i = sa.nz; i < 9; i++) sa.s[i] = sa.s[0];
    gemm8p<<<dim3(nb), 256, 0, stream>>>(sa);
    // L1
    nb = 0;
    for (int i = 0; i < cnt; i++){ int e = e0 + i;
      sa.s[i] = {h0buf + (size_t)i * sl0e, B_ew1 + (size_t)e * 512 * 2048, eb1 + e * 512,
                 h1buf + (size_t)i * sl1e, nullptr, nullptr, nullptr,
                 512, 1024, 2, 0, nb, 0};
      nb += NB1;
    }
    if (withGate){
      sa.s[cnt] = {h0g, B_gw1, gb1, h1g, nullptr, nullptr, nullptr,
                   512, 1024, 2, 0, nb, 0};
      nb += NB1;
    }
    gemm8p<<<dim3(nb), 256, 0, stream>>>(sa);
    // L2: experts fused-returns partials (mode 2); gate f32 h2 (mode 1)
    nb = 0;
    for (int i = 0; i < cnt; i++){ int e = e0 + i;
      sa.s[i] = {h1buf + (size_t)i * sl1e, B_ew2 + (size_t)e * 256 * 1024, eb2 + e * 256,
                 nullptr, ew3 + (size_t)e * 256, eb3 + e, ret2,
                 256, 512, 1, 2, nb, e};
      nb += NB2;
    }
    if (withGate){
      sa.s[cnt] = {h1g, B_gw2, gb2, h2g, nullptr, nullptr, nullptr,
                   256, 512, 1, 1, nb, 0};
      nb += NB2;
    }
    gemm8p<<<dim3(nb), 256, 0, stream>>>(sa);
    if (withGate)
      gate3_softmax<<<dim3(2048), 256, 0, stream>>>(h2g, gw3, gb3, wts);
  };

  if (gateFirst){
    SliceArr sa; sa.nz = 1;
    sa.s[0] = {A_code, B_gw0, gb0, h0g, nullptr, nullptr, nullptr, 1024, 64, 3, 0, 0, 0};
    for (int i = 1; i < 9; i++) sa.s[i] = sa.s[0];
    gemm8p<<<dim3(NB0), 256, 0, stream>>>(sa);
    sa.s[0] = {h0g, B_gw1, gb1, h1g, nullptr, nullptr, nullptr, 512, 1024, 2, 0, 0, 0};
    gemm8p<<<dim3(NB1), 256, 0, stream>>>(sa);
    sa.s[0] = {h1g, B_gw2, gb2, h2g, nullptr, nullptr, nullptr, 256, 512, 1, 1, 0, 0};
    gemm8p<<<dim3(NB2), 256, 0, stream>>>(sa);
    gate3_softmax<<<dim3(2048), 256, 0, stream>>>(h2g, gw3, gb3, wts);
    for (int e = 0; e < 8; e++) runGroup(e, 1, false);
  } else {
    bool first = true;
    for (int e0 = 0; e0 < 8; ){
      int cnt = (8 - e0 < G) ? (8 - e0) : G;
      runGroup(e0, cnt, first);
      first = false;
      e0 += cnt;
    }
  }

  combine<<<dim3(8192 / 256), 256, 0, stream>>>(wts, ret2, eb3, (float*)d_out);
}